// Round 1
// baseline (684.196 us; speedup 1.0000x reference)
//
#include <hip/hip_runtime.h>
#include <hip/hip_bf16.h>
#include <math.h>

#define F_IN 128
#define HID 32
#define HEADS 4
#define OUTC 16
#define NEG_SLOPE 0.2f
#define EPS_SM 1e-16f
#define BN_EPS 1e-5f

__device__ __forceinline__ float lrelu(float x) { return x > 0.f ? x : NEG_SLOPE * x; }
__device__ __forceinline__ float selc(float4 v, int i) {
    float r = v.x;
    r = (i == 1) ? v.y : r;
    r = (i == 2) ? v.z : r;
    r = (i == 3) ? v.w : r;
    return r;
}

// ---------------- GEMM: H[n,NC] = X[n,128] @ W[128,NC] ----------------
template <int NC, int ROWS, int NT, int KSTEP>
__global__ __launch_bounds__(NT) void gemm_k128(const float* __restrict__ X,
                                                const float* __restrict__ W,
                                                float* __restrict__ H, int n) {
    constexpr int CG = NC / 4;       // column groups (4 cols each)
    constexpr int RG = NT / CG;      // row groups
    constexpr int RPT = ROWS / RG;   // rows per thread
    __shared__ float Wl[KSTEP][NC];
    __shared__ float Xl[ROWS][128];
    int tid = threadIdx.x;
    long row0 = (long)blockIdx.x * ROWS;
    // stage X tile
    for (int i = tid; i < ROWS * 32; i += NT) {
        int r = i >> 5, q = i & 31;
        long gr = row0 + r;
        float4 v = make_float4(0.f, 0.f, 0.f, 0.f);
        if (gr < n) v = ((const float4*)(X + gr * 128))[q];
        ((float4*)&Xl[r][0])[q] = v;
    }
    int cg = tid % CG, rg = tid / CG;
    float acc[RPT][4] = {};
    for (int kb = 0; kb < 128; kb += KSTEP) {
        __syncthreads();
        for (int i = tid; i < KSTEP * NC / 4; i += NT)
            ((float4*)Wl)[i] = ((const float4*)(W + kb * NC))[i];
        __syncthreads();
        for (int kk = 0; kk < KSTEP; ++kk) {
            float4 w = *(const float4*)&Wl[kk][cg * 4];
            int k = kb + kk;
#pragma unroll
            for (int r = 0; r < RPT; ++r) {
                float xv = Xl[rg * RPT + r][k];
                acc[r][0] = fmaf(xv, w.x, acc[r][0]);
                acc[r][1] = fmaf(xv, w.y, acc[r][1]);
                acc[r][2] = fmaf(xv, w.z, acc[r][2]);
                acc[r][3] = fmaf(xv, w.w, acc[r][3]);
            }
        }
    }
    for (int r = 0; r < RPT; ++r) {
        long gr = row0 + rg * RPT + r;
        if (gr < n)
            *(float4*)&H[gr * NC + cg * 4] =
                make_float4(acc[r][0], acc[r][1], acc[r][2], acc[r][3]);
    }
}

// ---------------- per-node attention scores ----------------
template <int H, int C>
__global__ void scores_kernel(const float* __restrict__ h, const float* __restrict__ as_,
                              const float* __restrict__ ad_, float* __restrict__ ss,
                              float* __restrict__ sd, int n) {
    __shared__ float asl[H * C], adl[H * C];
    for (int i = threadIdx.x; i < H * C; i += blockDim.x) {
        asl[i] = as_[i];
        adl[i] = ad_[i];
    }
    __syncthreads();
    int node = blockIdx.x * blockDim.x + threadIdx.x;
    if (node >= n) return;
    const float* hp = h + (long)node * H * C;
    float s_[H] = {}, d_[H] = {};
#pragma unroll
    for (int q = 0; q < H * C / 4; ++q) {
        float4 hv = ((const float4*)hp)[q];
        float4 av = ((const float4*)asl)[q];
        float4 dv = ((const float4*)adl)[q];
        constexpr int CQ = C / 4;
        int head = q / CQ;
        s_[head] += hv.x * av.x + hv.y * av.y + hv.z * av.z + hv.w * av.w;
        d_[head] += hv.x * dv.x + hv.y * dv.y + hv.z * dv.z + hv.w * dv.w;
    }
#pragma unroll
    for (int hh = 0; hh < H; ++hh) {
        ss[(long)node * H + hh] = s_[hh];
        sd[(long)node * H + hh] = d_[hh];
    }
}

// ---------------- CSR build ----------------
__global__ void hist_kernel(const int* __restrict__ dst, int E, int* __restrict__ deg) {
    int i = blockIdx.x * blockDim.x + threadIdx.x;
    int T = gridDim.x * blockDim.x;
    for (; i < E; i += T) atomicAdd(&deg[dst[i]], 1);
}

__global__ __launch_bounds__(1024) void scan_kernel(const int* __restrict__ deg,
                                                    int* __restrict__ offs,
                                                    int* __restrict__ cur, int n) {
    __shared__ int wsum[16];
    __shared__ int wpre[16];
    __shared__ int carry_s;
    int tid = threadIdx.x;
    int lane = tid & 63;
    int w = tid >> 6;
    if (tid == 0) carry_s = 0;
    __syncthreads();
    for (int base = 0; base < n; base += 1024) {
        int carry = carry_s;
        int i = base + tid;
        int v = (i < n) ? deg[i] : 0;
        int incl = v;
#pragma unroll
        for (int d = 1; d < 64; d <<= 1) {
            int t = __shfl_up(incl, d, 64);
            if (lane >= d) incl += t;
        }
        if (lane == 63) wsum[w] = incl;
        __syncthreads();
        if (w == 0 && lane < 16) {
            int s = wsum[lane];
#pragma unroll
            for (int d = 1; d < 16; d <<= 1) {
                int t = __shfl_up(s, d, 64);
                if (lane >= d) s += t;
            }
            wpre[lane] = s;
        }
        __syncthreads();
        int wbase = (w == 0) ? 0 : wpre[w - 1];
        int excl = carry + wbase + incl - v;
        if (i < n) {
            offs[i] = excl;
            cur[i] = excl;
        }
        __syncthreads();
        if (tid == 1023) carry_s = carry + wpre[15];
        __syncthreads();
    }
}

__global__ void scatter_kernel(const int* __restrict__ dst, int E, int* __restrict__ cur,
                               int* __restrict__ ebd) {
    int i = blockIdx.x * blockDim.x + threadIdx.x;
    int T = gridDim.x * blockDim.x;
    for (; i < E; i += T) {
        int p = atomicAdd(&cur[dst[i]], 1);
        ebd[p] = i;
    }
}

// ---------------- GAT gather/aggregate: 4 heads x 32 ch ----------------
__global__ __launch_bounds__(256) void gat_gather4(
    const float* __restrict__ h, const float* __restrict__ ss, const float* __restrict__ sd,
    const int* __restrict__ offs, const int* __restrict__ deg, const int* __restrict__ ebd,
    const int* __restrict__ srcA, const float* __restrict__ bias, float* __restrict__ out,
    int n) {
    int wid = threadIdx.x >> 6;
    int lane = threadIdx.x & 63;
    int node = blockIdx.x * 4 + wid;
    if (node >= n) return;
    int off = offs[node];
    int dg = deg[node];
    int hd = lane >> 4;  // head owning this lane's 2 channels
    float4 sdn = *(const float4*)&sd[(long)node * 4];
    float4 ssn = *(const float4*)&ss[(long)node * 4];
    float4 es;  // self-loop scores
    es.x = lrelu(ssn.x + sdn.x);
    es.y = lrelu(ssn.y + sdn.y);
    es.z = lrelu(ssn.z + sdn.z);
    es.w = lrelu(ssn.w + sdn.w);
    // phase 1: max per head (init with self-loop)
    float4 mx = es;
    for (int i = lane; i < dg; i += 64) {
        int e = ebd[off + i];
        int s = srcA[e];
        float4 v = *(const float4*)&ss[(long)s * 4];
        mx.x = fmaxf(mx.x, lrelu(v.x + sdn.x));
        mx.y = fmaxf(mx.y, lrelu(v.y + sdn.y));
        mx.z = fmaxf(mx.z, lrelu(v.z + sdn.z));
        mx.w = fmaxf(mx.w, lrelu(v.w + sdn.w));
    }
#pragma unroll
    for (int d = 32; d >= 1; d >>= 1) {
        mx.x = fmaxf(mx.x, __shfl_xor(mx.x, d, 64));
        mx.y = fmaxf(mx.y, __shfl_xor(mx.y, d, 64));
        mx.z = fmaxf(mx.z, __shfl_xor(mx.z, d, 64));
        mx.w = fmaxf(mx.w, __shfl_xor(mx.w, d, 64));
    }
    // phase 2: sum of exp
    float4 sm = make_float4(0.f, 0.f, 0.f, 0.f);
    for (int i = lane; i < dg; i += 64) {
        int e = ebd[off + i];
        int s = srcA[e];
        float4 v = *(const float4*)&ss[(long)s * 4];
        sm.x += __expf(lrelu(v.x + sdn.x) - mx.x);
        sm.y += __expf(lrelu(v.y + sdn.y) - mx.y);
        sm.z += __expf(lrelu(v.z + sdn.z) - mx.z);
        sm.w += __expf(lrelu(v.w + sdn.w) - mx.w);
    }
#pragma unroll
    for (int d = 32; d >= 1; d >>= 1) {
        sm.x += __shfl_xor(sm.x, d, 64);
        sm.y += __shfl_xor(sm.y, d, 64);
        sm.z += __shfl_xor(sm.z, d, 64);
        sm.w += __shfl_xor(sm.w, d, 64);
    }
    sm.x += __expf(es.x - mx.x);
    sm.y += __expf(es.y - mx.y);
    sm.z += __expf(es.z - mx.z);
    sm.w += __expf(es.w - mx.w);
    float4 inv4 = make_float4(1.f / (sm.x + EPS_SM), 1.f / (sm.y + EPS_SM),
                              1.f / (sm.z + EPS_SM), 1.f / (sm.w + EPS_SM));
    float sdn_h = selc(sdn, hd);
    float mx_h = selc(mx, hd);
    float inv_h = selc(inv4, hd);
    // phase 3: weighted aggregate (2 channels per lane)
    float a0 = 0.f, a1 = 0.f;
    for (int i = 0; i < dg; ++i) {
        int e = ebd[off + i];
        int s = srcA[e];
        float esrc = ss[(long)s * 4 + hd];
        float alpha = __expf(lrelu(esrc + sdn_h) - mx_h) * inv_h;
        float2 hv = *(const float2*)&h[(long)s * 128 + lane * 2];
        a0 = fmaf(alpha, hv.x, a0);
        a1 = fmaf(alpha, hv.y, a1);
    }
    float alphaS = __expf(selc(es, hd) - mx_h) * inv_h;
    float2 hvS = *(const float2*)&h[(long)node * 128 + lane * 2];
    a0 = fmaf(alphaS, hvS.x, a0);
    a1 = fmaf(alphaS, hvS.y, a1);
    out[(long)node * 128 + lane * 2] = a0 + bias[lane * 2];
    out[(long)node * 128 + lane * 2 + 1] = a1 + bias[lane * 2 + 1];
}

// ---------------- GAT gather/aggregate: 1 head x 16 ch ----------------
__global__ __launch_bounds__(256) void gat_gather1(
    const float* __restrict__ h, const float* __restrict__ ss, const float* __restrict__ sd,
    const int* __restrict__ offs, const int* __restrict__ deg, const int* __restrict__ ebd,
    const int* __restrict__ srcA, const float* __restrict__ bias, float* __restrict__ out,
    int n) {
    int wid = threadIdx.x >> 6;
    int lane = threadIdx.x & 63;
    int node = blockIdx.x * 4 + wid;
    if (node >= n) return;
    int off = offs[node];
    int dg = deg[node];
    float sdn = sd[node];
    float ssn = ss[node];
    float eself = lrelu(ssn + sdn);
    float mx = eself;
    for (int i = lane; i < dg; i += 64) {
        int e = ebd[off + i];
        int s = srcA[e];
        mx = fmaxf(mx, lrelu(ss[s] + sdn));
    }
#pragma unroll
    for (int d = 32; d >= 1; d >>= 1) mx = fmaxf(mx, __shfl_xor(mx, d, 64));
    float sm = 0.f;
    for (int i = lane; i < dg; i += 64) {
        int e = ebd[off + i];
        int s = srcA[e];
        sm += __expf(lrelu(ss[s] + sdn) - mx);
    }
#pragma unroll
    for (int d = 32; d >= 1; d >>= 1) sm += __shfl_xor(sm, d, 64);
    sm += __expf(eself - mx);
    float inv = 1.f / (sm + EPS_SM);
    int c = lane & 15, g = lane >> 4;
    float acc = 0.f;
    for (int i = g; i < dg; i += 4) {
        int e = ebd[off + i];
        int s = srcA[e];
        float alpha = __expf(lrelu(ss[s] + sdn) - mx) * inv;
        acc = fmaf(alpha, h[(long)s * 16 + c], acc);
    }
    acc += __shfl_xor(acc, 16, 64);
    acc += __shfl_xor(acc, 32, 64);
    if (g == 0) {
        float alphaS = __expf(eself - mx) * inv;
        acc = fmaf(alphaS, h[(long)node * 16 + c], acc);
        out[(long)node * 16 + c] = acc + bias[c];
    }
}

// ---------------- BatchNorm stats + apply(ELU) ----------------
__global__ void bn_stats(const float* __restrict__ X, float* __restrict__ sums, int n) {
    long total = (long)n * 128;
    int T = gridDim.x * blockDim.x;  // multiple of 128
    long tid = (long)blockIdx.x * blockDim.x + threadIdx.x;
    int ch = (int)(tid & 127);
    float s = 0.f, s2 = 0.f;
    for (long i = tid; i < total; i += T) {
        float v = X[i];
        s += v;
        s2 = fmaf(v, v, s2);
    }
    atomicAdd(&sums[ch], s);
    atomicAdd(&sums[128 + ch], s2);
}

__global__ void bn_apply_elu(float* __restrict__ X, const float* __restrict__ sums,
                             const float* __restrict__ g, const float* __restrict__ be,
                             int n) {
    long total = (long)n * 128;
    int T = gridDim.x * blockDim.x;  // multiple of 128
    long tid = (long)blockIdx.x * blockDim.x + threadIdx.x;
    int ch = (int)(tid & 127);
    float inv_n = 1.f / (float)n;
    float m = sums[ch] * inv_n;
    float v = sums[128 + ch] * inv_n - m * m;
    float sc = rsqrtf(v + BN_EPS) * g[ch];
    float bb = be[ch];
    for (long i = tid; i < total; i += T) {
        float y = (X[i] - m) * sc + bb;
        X[i] = y > 0.f ? y : expm1f(y);
    }
}

extern "C" void kernel_launch(void* const* d_in, const int* in_sizes, int n_in,
                              void* d_out, int out_size, void* d_ws, size_t ws_size,
                              hipStream_t stream) {
    const float* x = (const float*)d_in[0];
    const int* ei = (const int*)d_in[1];
    const float* W0 = (const float*)d_in[2];
    const float* as0 = (const float*)d_in[3];
    const float* ad0 = (const float*)d_in[4];
    const float* b0 = (const float*)d_in[5];
    const float* g0 = (const float*)d_in[6];
    const float* be0 = (const float*)d_in[7];
    const float* W1 = (const float*)d_in[8];
    const float* as1 = (const float*)d_in[9];
    const float* ad1 = (const float*)d_in[10];
    const float* b1 = (const float*)d_in[11];
    const float* g1 = (const float*)d_in[12];
    const float* be1 = (const float*)d_in[13];
    const float* W2 = (const float*)d_in[14];
    const float* as2 = (const float*)d_in[15];
    const float* ad2 = (const float*)d_in[16];
    const float* b2 = (const float*)d_in[17];

    int n = in_sizes[0] / 128;
    int E = in_sizes[1] / 2;
    const int* srcA = ei;
    const int* dstA = ei + E;

    char* base = (char*)d_ws;
    auto alloc = [&](size_t bytes) {
        char* p = base;
        base += (bytes + 255) & ~(size_t)255;
        return p;
    };
    float* h = (float*)alloc((size_t)n * 128 * 4);
    float* act = (float*)alloc((size_t)n * 128 * 4);
    float* ssb = (float*)alloc((size_t)n * 4 * 4);
    float* sdb = (float*)alloc((size_t)n * 4 * 4);
    float* sums = (float*)alloc(256 * 4);
    int* deg = (int*)alloc((size_t)n * 4);
    int* offs = (int*)alloc((size_t)n * 4);
    int* cur = (int*)alloc((size_t)n * 4);
    int* ebd = (int*)alloc((size_t)E * 4);

    float* out = (float*)d_out;

    // ---- CSR build (edge_index is layer-invariant) ----
    hipMemsetAsync(deg, 0, (size_t)n * 4, stream);
    hist_kernel<<<1024, 256, 0, stream>>>(dstA, E, deg);
    scan_kernel<<<1, 1024, 0, stream>>>(deg, offs, cur, n);
    scatter_kernel<<<1024, 256, 0, stream>>>(dstA, E, cur, ebd);

    int gGemm128 = (n + 31) / 32;
    int gGemm16 = (n + 63) / 64;
    int gNode = (n + 255) / 256;
    int gWave = (n + 3) / 4;

    // ---- layer 0 ----
    gemm_k128<128, 32, 256, 64><<<gGemm128, 256, 0, stream>>>(x, W0, h, n);
    scores_kernel<4, 32><<<gNode, 256, 0, stream>>>(h, as0, ad0, ssb, sdb, n);
    gat_gather4<<<gWave, 256, 0, stream>>>(h, ssb, sdb, offs, deg, ebd, srcA, b0, act, n);
    hipMemsetAsync(sums, 0, 256 * 4, stream);
    bn_stats<<<512, 256, 0, stream>>>(act, sums, n);
    bn_apply_elu<<<2048, 256, 0, stream>>>(act, sums, g0, be0, n);

    // ---- layer 1 ----
    gemm_k128<128, 32, 256, 64><<<gGemm128, 256, 0, stream>>>(act, W1, h, n);
    scores_kernel<4, 32><<<gNode, 256, 0, stream>>>(h, as1, ad1, ssb, sdb, n);
    gat_gather4<<<gWave, 256, 0, stream>>>(h, ssb, sdb, offs, deg, ebd, srcA, b1, act, n);
    hipMemsetAsync(sums, 0, 256 * 4, stream);
    bn_stats<<<512, 256, 0, stream>>>(act, sums, n);
    bn_apply_elu<<<2048, 256, 0, stream>>>(act, sums, g1, be1, n);

    // ---- layer 2 ----
    gemm_k128<16, 64, 128, 128><<<gGemm16, 128, 0, stream>>>(act, W2, h, n);
    scores_kernel<1, 16><<<gNode, 256, 0, stream>>>(h, as2, ad2, ssb, sdb, n);
    gat_gather1<<<gWave, 256, 0, stream>>>(h, ssb, sdb, offs, deg, ebd, srcA, b2, out, n);
}

// Round 2
// 488.081 us; speedup vs baseline: 1.4018x; 1.4018x over previous
//
#include <hip/hip_runtime.h>
#include <hip/hip_bf16.h>
#include <math.h>

#define NEG_SLOPE 0.2f
#define EPS_SM 1e-16f
#define BN_EPS 1e-5f

__device__ __forceinline__ float lrelu(float x) { return x > 0.f ? x : NEG_SLOPE * x; }
__device__ __forceinline__ float selc(float4 v, int i) {
    float r = v.x;
    r = (i == 1) ? v.y : r;
    r = (i == 2) ? v.z : r;
    r = (i == 3) ? v.w : r;
    return r;
}
// fp32 -> bf16 round-to-nearest-even (bit math, no API dependency)
__device__ __forceinline__ ushort f2bf(float f) {
    uint u = __float_as_uint(f);
    return (ushort)((u + 0x7FFFu + ((u >> 16) & 1u)) >> 16);
}
__device__ __forceinline__ float bfl(uint u) { return __uint_as_float(u << 16); }
__device__ __forceinline__ float bfh(uint u) { return __uint_as_float(u & 0xFFFF0000u); }

// ---------------- GEMM: Hb[n,NC](bf16) = bnelu?(X[n,128]) @ W[128,NC] ----------------
template <int NC, int ROWS, int NT, int KSTEP, bool BNELU>
__global__ __launch_bounds__(NT) void gemm_k128(const float* __restrict__ X,
                                                const float* __restrict__ W,
                                                ushort* __restrict__ Hb, int n,
                                                const float* __restrict__ sums,
                                                const float* __restrict__ g,
                                                const float* __restrict__ be) {
    constexpr int CG = NC / 4;      // column groups (4 cols each)
    constexpr int RG = NT / CG;     // row groups
    constexpr int RPT = ROWS / RG;  // rows per thread
    __shared__ float Wl[KSTEP][NC];
    __shared__ float Xl[ROWS][128];
    int tid = threadIdx.x;
    int row0 = blockIdx.x * ROWS;
    float inv_n = 1.f / (float)n;
    // stage X tile (optionally fused BatchNorm + ELU on the fly)
    for (int i = tid; i < ROWS * 32; i += NT) {
        int r = i >> 5, q = i & 31;
        int gr = row0 + r;
        float4 v = make_float4(0.f, 0.f, 0.f, 0.f);
        if (gr < n) v = ((const float4*)(X + (long)gr * 128))[q];
        if constexpr (BNELU) {
            int c0 = q * 4;
            float m, vv, sc, y;
            m = sums[c0] * inv_n; vv = fmaxf(sums[128 + c0] * inv_n - m * m, 0.f);
            sc = rsqrtf(vv + BN_EPS) * g[c0]; y = (v.x - m) * sc + be[c0];
            v.x = y > 0.f ? y : expm1f(y);
            m = sums[c0 + 1] * inv_n; vv = fmaxf(sums[129 + c0] * inv_n - m * m, 0.f);
            sc = rsqrtf(vv + BN_EPS) * g[c0 + 1]; y = (v.y - m) * sc + be[c0 + 1];
            v.y = y > 0.f ? y : expm1f(y);
            m = sums[c0 + 2] * inv_n; vv = fmaxf(sums[130 + c0] * inv_n - m * m, 0.f);
            sc = rsqrtf(vv + BN_EPS) * g[c0 + 2]; y = (v.z - m) * sc + be[c0 + 2];
            v.z = y > 0.f ? y : expm1f(y);
            m = sums[c0 + 3] * inv_n; vv = fmaxf(sums[131 + c0] * inv_n - m * m, 0.f);
            sc = rsqrtf(vv + BN_EPS) * g[c0 + 3]; y = (v.w - m) * sc + be[c0 + 3];
            v.w = y > 0.f ? y : expm1f(y);
        }
        ((float4*)&Xl[r][0])[q] = v;
    }
    int cg = tid % CG, rg = tid / CG;
    float acc[RPT][4] = {};
    for (int kb = 0; kb < 128; kb += KSTEP) {
        __syncthreads();
        for (int i = tid; i < KSTEP * NC / 4; i += NT)
            ((float4*)Wl)[i] = ((const float4*)(W + kb * NC))[i];
        __syncthreads();
        for (int kk = 0; kk < KSTEP; ++kk) {
            float4 w = *(const float4*)&Wl[kk][cg * 4];
            int k = kb + kk;
#pragma unroll
            for (int r = 0; r < RPT; ++r) {
                float xv = Xl[rg * RPT + r][k];
                acc[r][0] = fmaf(xv, w.x, acc[r][0]);
                acc[r][1] = fmaf(xv, w.y, acc[r][1]);
                acc[r][2] = fmaf(xv, w.z, acc[r][2]);
                acc[r][3] = fmaf(xv, w.w, acc[r][3]);
            }
        }
    }
    for (int r = 0; r < RPT; ++r) {
        int gr = row0 + rg * RPT + r;
        if (gr < n) {
            uint2 p;
            p.x = (uint)f2bf(acc[r][0]) | ((uint)f2bf(acc[r][1]) << 16);
            p.y = (uint)f2bf(acc[r][2]) | ((uint)f2bf(acc[r][3]) << 16);
            *(uint2*)&Hb[(long)gr * NC + cg * 4] = p;
        }
    }
}

// ---------------- per-node attention scores (reads bf16 h) ----------------
template <int H, int C>
__global__ void scores_kernel(const uint* __restrict__ hb, const float* __restrict__ as_,
                              const float* __restrict__ ad_, float* __restrict__ ss,
                              float* __restrict__ sd, int n) {
    __shared__ float asl[H * C], adl[H * C];
    for (int i = threadIdx.x; i < H * C; i += blockDim.x) {
        asl[i] = as_[i];
        adl[i] = ad_[i];
    }
    __syncthreads();
    int node = blockIdx.x * blockDim.x + threadIdx.x;
    if (node >= n) return;
    const uint* hp = hb + (long)node * (H * C / 2);
    float s_[H] = {}, d_[H] = {};
#pragma unroll 8
    for (int q = 0; q < H * C / 2; ++q) {
        uint hv = hp[q];
        float lo = bfl(hv), hi = bfh(hv);
        int ch = q * 2, head = ch / C;
        s_[head] += lo * asl[ch] + hi * asl[ch + 1];
        d_[head] += lo * adl[ch] + hi * adl[ch + 1];
    }
#pragma unroll
    for (int hh = 0; hh < H; ++hh) {
        ss[(long)node * H + hh] = s_[hh];
        sd[(long)node * H + hh] = d_[hh];
    }
}

// ---------------- CSR build ----------------
__global__ void hist_kernel(const int* __restrict__ dst, int E, int* __restrict__ deg) {
    int i = blockIdx.x * blockDim.x + threadIdx.x;
    int T = gridDim.x * blockDim.x;
    for (; i < E; i += T) atomicAdd(&deg[dst[i]], 1);
}

__global__ __launch_bounds__(1024) void scan_kernel(const int* __restrict__ deg,
                                                    int* __restrict__ offs,
                                                    int* __restrict__ cur, int n) {
    __shared__ int wsum[16];
    __shared__ int wpre[16];
    __shared__ int carry_s;
    int tid = threadIdx.x;
    int lane = tid & 63;
    int w = tid >> 6;
    if (tid == 0) carry_s = 0;
    __syncthreads();
    for (int base = 0; base < n; base += 1024) {
        int carry = carry_s;
        int i = base + tid;
        int v = (i < n) ? deg[i] : 0;
        int incl = v;
#pragma unroll
        for (int d = 1; d < 64; d <<= 1) {
            int t = __shfl_up(incl, d, 64);
            if (lane >= d) incl += t;
        }
        if (lane == 63) wsum[w] = incl;
        __syncthreads();
        if (w == 0 && lane < 16) {
            int s = wsum[lane];
#pragma unroll
            for (int d = 1; d < 16; d <<= 1) {
                int t = __shfl_up(s, d, 64);
                if (lane >= d) s += t;
            }
            wpre[lane] = s;
        }
        __syncthreads();
        int wbase = (w == 0) ? 0 : wpre[w - 1];
        int excl = carry + wbase + incl - v;
        if (i < n) {
            offs[i] = excl;
            cur[i] = excl;
        }
        __syncthreads();
        if (tid == 1023) carry_s = carry + wpre[15];
        __syncthreads();
    }
}

// store src node directly (kills the ebd->srcA double indirection)
__global__ void scatter_kernel(const int* __restrict__ src, const int* __restrict__ dst,
                               int E, int* __restrict__ cur, int* __restrict__ srcs) {
    int i = blockIdx.x * blockDim.x + threadIdx.x;
    int T = gridDim.x * blockDim.x;
    for (; i < E; i += T) {
        int p = atomicAdd(&cur[dst[i]], 1);
        srcs[p] = src[i];
    }
}

// ---------------- GAT gather/aggregate: 4 heads x 32 ch (bf16 h) ----------------
__global__ __launch_bounds__(256) void gat_gather4(
    const uint* __restrict__ hb, const float* __restrict__ ss, const float* __restrict__ sd,
    const int* __restrict__ offs, const int* __restrict__ deg, const int* __restrict__ srcs,
    const float* __restrict__ bias, float* __restrict__ out, int n) {
    int wid = threadIdx.x >> 6;
    int lane = threadIdx.x & 63;
    int node = blockIdx.x * 4 + wid;
    if (node >= n) return;
    int off = offs[node];
    int dg = deg[node];
    int hd = lane >> 4;
    float4 sdn = *(const float4*)&sd[node * 4];
    float4 ssn = *(const float4*)&ss[node * 4];
    float4 es;  // self-loop scores (no max subtraction: softmax is shift-invariant,
                // scores are bounded so exp() stays in fp32 range)
    es.x = lrelu(ssn.x + sdn.x);
    es.y = lrelu(ssn.y + sdn.y);
    es.z = lrelu(ssn.z + sdn.z);
    es.w = lrelu(ssn.w + sdn.w);
    // pass A: denominators
    float4 sm = make_float4(0.f, 0.f, 0.f, 0.f);
    for (int i = lane; i < dg; i += 64) {
        int s = srcs[off + i];
        float4 v = *(const float4*)&ss[s * 4];
        sm.x += __expf(lrelu(v.x + sdn.x));
        sm.y += __expf(lrelu(v.y + sdn.y));
        sm.z += __expf(lrelu(v.z + sdn.z));
        sm.w += __expf(lrelu(v.w + sdn.w));
    }
#pragma unroll
    for (int d = 32; d >= 1; d >>= 1) {
        sm.x += __shfl_xor(sm.x, d, 64);
        sm.y += __shfl_xor(sm.y, d, 64);
        sm.z += __shfl_xor(sm.z, d, 64);
        sm.w += __shfl_xor(sm.w, d, 64);
    }
    sm.x += __expf(es.x);
    sm.y += __expf(es.y);
    sm.z += __expf(es.z);
    sm.w += __expf(es.w);
    float4 inv4 = make_float4(1.f / (sm.x + EPS_SM), 1.f / (sm.y + EPS_SM),
                              1.f / (sm.z + EPS_SM), 1.f / (sm.w + EPS_SM));
    float sdn_h = selc(sdn, hd);
    float inv_h = selc(inv4, hd);
    float es_h = selc(es, hd);
    // pass B: weighted aggregate, inv factored out (2 bf16 channels per lane)
    float a0 = 0.f, a1 = 0.f;
#pragma unroll 2
    for (int i = 0; i < dg; ++i) {
        int s = srcs[off + i];
        float4 v = *(const float4*)&ss[s * 4];  // wave-uniform broadcast load
        float w = __expf(lrelu(selc(v, hd) + sdn_h));
        uint hv = hb[s * 64 + lane];
        a0 = fmaf(w, bfl(hv), a0);
        a1 = fmaf(w, bfh(hv), a1);
    }
    float wS = __expf(es_h);
    uint hvS = hb[node * 64 + lane];
    a0 = fmaf(wS, bfl(hvS), a0);
    a1 = fmaf(wS, bfh(hvS), a1);
    out[(long)node * 128 + lane * 2] = a0 * inv_h + bias[lane * 2];
    out[(long)node * 128 + lane * 2 + 1] = a1 * inv_h + bias[lane * 2 + 1];
}

// ---------------- GAT gather/aggregate: 1 head x 16 ch (bf16 h) ----------------
__global__ __launch_bounds__(256) void gat_gather1(
    const ushort* __restrict__ hb, const float* __restrict__ ss, const float* __restrict__ sd,
    const int* __restrict__ offs, const int* __restrict__ deg, const int* __restrict__ srcs,
    const float* __restrict__ bias, float* __restrict__ out, int n) {
    int wid = threadIdx.x >> 6;
    int lane = threadIdx.x & 63;
    int node = blockIdx.x * 4 + wid;
    if (node >= n) return;
    int off = offs[node];
    int dg = deg[node];
    float sdn = sd[node];
    float eself = lrelu(ss[node] + sdn);
    float sm = 0.f;
    for (int i = lane; i < dg; i += 64) {
        int s = srcs[off + i];
        sm += __expf(lrelu(ss[s] + sdn));
    }
#pragma unroll
    for (int d = 32; d >= 1; d >>= 1) sm += __shfl_xor(sm, d, 64);
    sm += __expf(eself);
    float inv = 1.f / (sm + EPS_SM);
    int c = lane & 15, gq = lane >> 4;
    float acc = 0.f;
    for (int i = gq; i < dg; i += 4) {
        int s = srcs[off + i];
        float w = __expf(lrelu(ss[s] + sdn));
        acc = fmaf(w, __uint_as_float(((uint)hb[s * 16 + c]) << 16), acc);
    }
    acc += __shfl_xor(acc, 16, 64);
    acc += __shfl_xor(acc, 32, 64);
    if (gq == 0) {
        float wS = __expf(eself);
        acc = fmaf(wS, __uint_as_float(((uint)hb[node * 16 + c]) << 16), acc);
        out[(long)node * 16 + c] = acc * inv + bias[c];
    }
}

// ---------------- BatchNorm stats ----------------
__global__ void bn_stats(const float* __restrict__ X, float* __restrict__ sums, int n) {
    long total = (long)n * 128;
    int T = gridDim.x * blockDim.x;  // multiple of 128
    long tid = (long)blockIdx.x * blockDim.x + threadIdx.x;
    int ch = (int)(tid & 127);
    float s = 0.f, s2 = 0.f;
    for (long i = tid; i < total; i += T) {
        float v = X[i];
        s += v;
        s2 = fmaf(v, v, s2);
    }
    atomicAdd(&sums[ch], s);
    atomicAdd(&sums[128 + ch], s2);
}

extern "C" void kernel_launch(void* const* d_in, const int* in_sizes, int n_in,
                              void* d_out, int out_size, void* d_ws, size_t ws_size,
                              hipStream_t stream) {
    const float* x = (const float*)d_in[0];
    const int* ei = (const int*)d_in[1];
    const float* W0 = (const float*)d_in[2];
    const float* as0 = (const float*)d_in[3];
    const float* ad0 = (const float*)d_in[4];
    const float* b0 = (const float*)d_in[5];
    const float* g0 = (const float*)d_in[6];
    const float* be0 = (const float*)d_in[7];
    const float* W1 = (const float*)d_in[8];
    const float* as1 = (const float*)d_in[9];
    const float* ad1 = (const float*)d_in[10];
    const float* b1 = (const float*)d_in[11];
    const float* g1 = (const float*)d_in[12];
    const float* be1 = (const float*)d_in[13];
    const float* W2 = (const float*)d_in[14];
    const float* as2 = (const float*)d_in[15];
    const float* ad2 = (const float*)d_in[16];
    const float* b2 = (const float*)d_in[17];

    int n = in_sizes[0] / 128;
    int E = in_sizes[1] / 2;
    const int* srcA = ei;
    const int* dstA = ei + E;

    char* base = (char*)d_ws;
    auto alloc = [&](size_t bytes) {
        char* p = base;
        base += (bytes + 255) & ~(size_t)255;
        return p;
    };
    ushort* hb = (ushort*)alloc((size_t)n * 128 * 2);  // bf16 h (layers 0/1)
    float* act = (float*)alloc((size_t)n * 128 * 4);   // fp32 aggregate (BN input)
    ushort* h2b = (ushort*)alloc((size_t)n * 16 * 2);  // bf16 h (layer 2)
    float* ssb = (float*)alloc((size_t)n * 4 * 4);
    float* sdb = (float*)alloc((size_t)n * 4 * 4);
    float* sums = (float*)alloc(256 * 4);
    int* deg = (int*)alloc((size_t)n * 4);
    int* offs = (int*)alloc((size_t)n * 4);
    int* cur = (int*)alloc((size_t)n * 4);
    int* srcs = (int*)alloc((size_t)E * 4);

    float* out = (float*)d_out;

    // ---- CSR build (edge_index is layer-invariant) ----
    hipMemsetAsync(deg, 0, (size_t)n * 4, stream);
    hist_kernel<<<1024, 256, 0, stream>>>(dstA, E, deg);
    scan_kernel<<<1, 1024, 0, stream>>>(deg, offs, cur, n);
    scatter_kernel<<<1024, 256, 0, stream>>>(srcA, dstA, E, cur, srcs);

    int gGemm128 = (n + 31) / 32;
    int gGemm16 = (n + 63) / 64;
    int gNode = (n + 255) / 256;
    int gWave = (n + 3) / 4;

    // ---- layer 0 ----
    gemm_k128<128, 32, 256, 64, false><<<gGemm128, 256, 0, stream>>>(x, W0, hb, n, sums, g0, be0);
    scores_kernel<4, 32><<<gNode, 256, 0, stream>>>((const uint*)hb, as0, ad0, ssb, sdb, n);
    gat_gather4<<<gWave, 256, 0, stream>>>((const uint*)hb, ssb, sdb, offs, deg, srcs, b0, act, n);
    hipMemsetAsync(sums, 0, 256 * 4, stream);
    bn_stats<<<512, 256, 0, stream>>>(act, sums, n);

    // ---- layer 1 (BN+ELU fused into GEMM X-staging) ----
    gemm_k128<128, 32, 256, 64, true><<<gGemm128, 256, 0, stream>>>(act, W1, hb, n, sums, g0, be0);
    scores_kernel<4, 32><<<gNode, 256, 0, stream>>>((const uint*)hb, as1, ad1, ssb, sdb, n);
    gat_gather4<<<gWave, 256, 0, stream>>>((const uint*)hb, ssb, sdb, offs, deg, srcs, b1, act, n);
    hipMemsetAsync(sums, 0, 256 * 4, stream);
    bn_stats<<<512, 256, 0, stream>>>(act, sums, n);

    // ---- layer 2 ----
    gemm_k128<16, 64, 128, 128, true><<<gGemm16, 128, 0, stream>>>(act, W2, h2b, n, sums, g1, be1);
    scores_kernel<1, 16><<<gNode, 256, 0, stream>>>((const uint*)h2b, as2, ad2, ssb, sdb, n);
    gat_gather1<<<gWave, 256, 0, stream>>>(h2b, ssb, sdb, offs, deg, srcs, b2, out, n);
}

// Round 3
// 409.381 us; speedup vs baseline: 1.6713x; 1.1922x over previous
//
#include <hip/hip_runtime.h>
#include <hip/hip_bf16.h>
#include <math.h>

#define NEG_SLOPE 0.2f
#define EPS_SM 1e-16f
#define BN_EPS 1e-5f

__device__ __forceinline__ float lrelu(float x) { return x > 0.f ? x : NEG_SLOPE * x; }
// fp32 -> bf16 round-to-nearest-even
__device__ __forceinline__ ushort f2bf(float f) {
    uint u = __float_as_uint(f);
    return (ushort)((u + 0x7FFFu + ((u >> 16) & 1u)) >> 16);
}
__device__ __forceinline__ float bfl(uint u) { return __uint_as_float(u << 16); }
__device__ __forceinline__ float bfh(uint u) { return __uint_as_float(u & 0xFFFF0000u); }

// ---- GEMM: Hb[n,NC](bf16) = bnelu?(X[n,128]) @ W[128,NC], scores fused in epilogue ----
template <int NC, int ROWS, int NT, int KSTEP, bool BNELU, int HEADS>
__global__ __launch_bounds__(NT) void gemm_k128(
    const float* __restrict__ X, const float* __restrict__ W, ushort* __restrict__ Hb, int n,
    const float* __restrict__ sums, const float* __restrict__ g, const float* __restrict__ be,
    const float* __restrict__ as_, const float* __restrict__ ad_,
    float* __restrict__ ss, float* __restrict__ sd) {
    constexpr int CG = NC / 4;      // column groups (4 cols each)
    constexpr int RG = NT / CG;     // row groups
    constexpr int RPT = ROWS / RG;  // rows per thread
    constexpr int C = NC / HEADS;   // channels per head
    constexpr int TPH = C / 4;      // threads covering one head's channels
    __shared__ float Wl[KSTEP][NC];
    __shared__ float Xl[ROWS][128];
    int tid = threadIdx.x;
    int row0 = blockIdx.x * ROWS;
    float inv_n = 1.f / (float)n;
    // stage X tile (optionally fused BatchNorm + ELU)
    for (int i = tid; i < ROWS * 32; i += NT) {
        int r = i >> 5, q = i & 31;
        int gr = row0 + r;
        float4 v = make_float4(0.f, 0.f, 0.f, 0.f);
        if (gr < n) v = ((const float4*)(X + (long)gr * 128))[q];
        if constexpr (BNELU) {
            int c0 = q * 4;
            float m, vv, sc, y;
            m = sums[c0] * inv_n; vv = fmaxf(sums[128 + c0] * inv_n - m * m, 0.f);
            sc = rsqrtf(vv + BN_EPS) * g[c0]; y = (v.x - m) * sc + be[c0];
            v.x = y > 0.f ? y : expm1f(y);
            m = sums[c0 + 1] * inv_n; vv = fmaxf(sums[129 + c0] * inv_n - m * m, 0.f);
            sc = rsqrtf(vv + BN_EPS) * g[c0 + 1]; y = (v.y - m) * sc + be[c0 + 1];
            v.y = y > 0.f ? y : expm1f(y);
            m = sums[c0 + 2] * inv_n; vv = fmaxf(sums[130 + c0] * inv_n - m * m, 0.f);
            sc = rsqrtf(vv + BN_EPS) * g[c0 + 2]; y = (v.z - m) * sc + be[c0 + 2];
            v.z = y > 0.f ? y : expm1f(y);
            m = sums[c0 + 3] * inv_n; vv = fmaxf(sums[131 + c0] * inv_n - m * m, 0.f);
            sc = rsqrtf(vv + BN_EPS) * g[c0 + 3]; y = (v.w - m) * sc + be[c0 + 3];
            v.w = y > 0.f ? y : expm1f(y);
        }
        ((float4*)&Xl[r][0])[q] = v;
    }
    int cg = tid % CG, rg = tid / CG;
    float acc[RPT][4] = {};
    for (int kb = 0; kb < 128; kb += KSTEP) {
        __syncthreads();
        for (int i = tid; i < KSTEP * NC / 4; i += NT)
            ((float4*)Wl)[i] = ((const float4*)(W + kb * NC))[i];
        __syncthreads();
        for (int kk = 0; kk < KSTEP; ++kk) {
            float4 w = *(const float4*)&Wl[kk][cg * 4];
            int k = kb + kk;
#pragma unroll
            for (int r = 0; r < RPT; ++r) {
                float xv = Xl[rg * RPT + r][k];
                acc[r][0] = fmaf(xv, w.x, acc[r][0]);
                acc[r][1] = fmaf(xv, w.y, acc[r][1]);
                acc[r][2] = fmaf(xv, w.z, acc[r][2]);
                acc[r][3] = fmaf(xv, w.w, acc[r][3]);
            }
        }
    }
    // write bf16 h
#pragma unroll
    for (int r = 0; r < RPT; ++r) {
        int gr = row0 + rg * RPT + r;
        if (gr < n) {
            uint2 p;
            p.x = (uint)f2bf(acc[r][0]) | ((uint)f2bf(acc[r][1]) << 16);
            p.y = (uint)f2bf(acc[r][2]) | ((uint)f2bf(acc[r][3]) << 16);
            *(uint2*)&Hb[(long)gr * NC + cg * 4] = p;
        }
    }
    // fused attention scores: reduce over the TPH threads covering one head
    int head = cg / TPH;
    float4 av = *(const float4*)&as_[cg * 4];
    float4 dv = *(const float4*)&ad_[cg * 4];
#pragma unroll
    for (int r = 0; r < RPT; ++r) {
        float ps = acc[r][0] * av.x + acc[r][1] * av.y + acc[r][2] * av.z + acc[r][3] * av.w;
        float pd = acc[r][0] * dv.x + acc[r][1] * dv.y + acc[r][2] * dv.z + acc[r][3] * dv.w;
#pragma unroll
        for (int d = 1; d < TPH; d <<= 1) {
            ps += __shfl_xor(ps, d, 64);
            pd += __shfl_xor(pd, d, 64);
        }
        int gr = row0 + rg * RPT + r;
        if ((cg & (TPH - 1)) == 0 && gr < n) {
            ss[(long)gr * HEADS + head] = ps;
            sd[(long)gr * HEADS + head] = pd;
        }
    }
}

// ---------------- CSR build ----------------
__global__ void hist_kernel(const int* __restrict__ dst, int E, int* __restrict__ deg) {
    int i = blockIdx.x * blockDim.x + threadIdx.x;
    int T = gridDim.x * blockDim.x;
    for (; i < E; i += T) atomicAdd(&deg[dst[i]], 1);
}

__global__ __launch_bounds__(1024) void scan_kernel(const int* __restrict__ deg,
                                                    int* __restrict__ offs,
                                                    int* __restrict__ cur, int n) {
    __shared__ int wsum[16];
    __shared__ int wpre[16];
    __shared__ int carry_s;
    int tid = threadIdx.x;
    int lane = tid & 63;
    int w = tid >> 6;
    if (tid == 0) carry_s = 0;
    __syncthreads();
    for (int base = 0; base < n; base += 1024) {
        int carry = carry_s;
        int i = base + tid;
        int v = (i < n) ? deg[i] : 0;
        int incl = v;
#pragma unroll
        for (int d = 1; d < 64; d <<= 1) {
            int t = __shfl_up(incl, d, 64);
            if (lane >= d) incl += t;
        }
        if (lane == 63) wsum[w] = incl;
        __syncthreads();
        if (w == 0 && lane < 16) {
            int s = wsum[lane];
#pragma unroll
            for (int d = 1; d < 16; d <<= 1) {
                int t = __shfl_up(s, d, 64);
                if (lane >= d) s += t;
            }
            wpre[lane] = s;
        }
        __syncthreads();
        int wbase = (w == 0) ? 0 : wpre[w - 1];
        int excl = carry + wbase + incl - v;
        if (i < n) {
            offs[i] = excl;
            cur[i] = excl;
        }
        __syncthreads();
        if (tid == 1023) carry_s = carry + wpre[15];
        __syncthreads();
    }
}

__global__ void scatter_kernel(const int* __restrict__ src, const int* __restrict__ dst,
                               int E, int* __restrict__ cur, int* __restrict__ srcs) {
    int i = blockIdx.x * blockDim.x + threadIdx.x;
    int T = gridDim.x * blockDim.x;
    for (; i < E; i += T) {
        int p = atomicAdd(&cur[dst[i]], 1);
        srcs[p] = src[i];
    }
}

// ---- GAT gather, 4 heads x 32ch: single pass, 4 edge-groups x 16 lanes x 8ch ----
__global__ __launch_bounds__(256) void gat_gather4(
    const uint* __restrict__ hb, const float* __restrict__ ss, const float* __restrict__ sd,
    const int* __restrict__ offs, const int* __restrict__ deg, const int* __restrict__ srcs,
    const float* __restrict__ bias, float* __restrict__ out, int n) {
    int wid = threadIdx.x >> 6;
    int lane = threadIdx.x & 63;
    int node = blockIdx.x * 4 + wid;
    if (node >= n) return;
    int off = offs[node];
    int dg = deg[node];
    int grp = lane >> 4;   // edge group (4 edges in flight per wave)
    int ll = lane & 15;    // channels ll*8 .. ll*8+7
    int hd = ll >> 2;      // head of those channels
    float sdn = sd[node * 4 + hd];
    float es = lrelu(ss[node * 4 + hd] + sdn);  // self-loop score (no max shift:
                                                // softmax shift-invariant, scores bounded)
    const uint* hrow = hb + ll * 4;
    float acc[8] = {};
    float sm = 0.f;
#pragma unroll 2
    for (int i = grp; i < dg; i += 4) {
        int s = srcs[off + i];
        float w = __expf(lrelu(ss[s * 4 + hd] + sdn));
        sm += w;
        uint4 hv = *(const uint4*)(hrow + (long)s * 64);
        acc[0] = fmaf(w, bfl(hv.x), acc[0]);
        acc[1] = fmaf(w, bfh(hv.x), acc[1]);
        acc[2] = fmaf(w, bfl(hv.y), acc[2]);
        acc[3] = fmaf(w, bfh(hv.y), acc[3]);
        acc[4] = fmaf(w, bfl(hv.z), acc[4]);
        acc[5] = fmaf(w, bfh(hv.z), acc[5]);
        acc[6] = fmaf(w, bfl(hv.w), acc[6]);
        acc[7] = fmaf(w, bfh(hv.w), acc[7]);
    }
    // reduce the 4 edge groups (lanes l, l^16, l^32, l^48 hold partials for same channels)
#pragma unroll
    for (int j = 0; j < 8; ++j) {
        acc[j] += __shfl_xor(acc[j], 16, 64);
        acc[j] += __shfl_xor(acc[j], 32, 64);
    }
    sm += __shfl_xor(sm, 16, 64);
    sm += __shfl_xor(sm, 32, 64);
    // self loop
    float wS = __expf(es);
    sm += wS;
    uint4 hvS = *(const uint4*)(hrow + (long)node * 64);
    acc[0] = fmaf(wS, bfl(hvS.x), acc[0]);
    acc[1] = fmaf(wS, bfh(hvS.x), acc[1]);
    acc[2] = fmaf(wS, bfl(hvS.y), acc[2]);
    acc[3] = fmaf(wS, bfh(hvS.y), acc[3]);
    acc[4] = fmaf(wS, bfl(hvS.z), acc[4]);
    acc[5] = fmaf(wS, bfh(hvS.z), acc[5]);
    acc[6] = fmaf(wS, bfl(hvS.w), acc[6]);
    acc[7] = fmaf(wS, bfh(hvS.w), acc[7]);
    float inv = 1.f / (sm + EPS_SM);
    if (grp == 0) {
        float4 bA = *(const float4*)&bias[ll * 8];
        float4 bB = *(const float4*)&bias[ll * 8 + 4];
        float4 o0 = make_float4(acc[0] * inv + bA.x, acc[1] * inv + bA.y,
                                acc[2] * inv + bA.z, acc[3] * inv + bA.w);
        float4 o1 = make_float4(acc[4] * inv + bB.x, acc[5] * inv + bB.y,
                                acc[6] * inv + bB.z, acc[7] * inv + bB.w);
        *(float4*)&out[(long)node * 128 + ll * 8] = o0;
        *(float4*)&out[(long)node * 128 + ll * 8 + 4] = o1;
    }
}

// ---- GAT gather, 1 head x 16ch: single pass, 8 edge-groups x 8 lanes x 2ch ----
__global__ __launch_bounds__(256) void gat_gather1(
    const uint* __restrict__ hb2, const float* __restrict__ ss, const float* __restrict__ sd,
    const int* __restrict__ offs, const int* __restrict__ deg, const int* __restrict__ srcs,
    const float* __restrict__ bias, float* __restrict__ out, int n) {
    int wid = threadIdx.x >> 6;
    int lane = threadIdx.x & 63;
    int node = blockIdx.x * 4 + wid;
    if (node >= n) return;
    int off = offs[node];
    int dg = deg[node];
    int grp = lane >> 3;  // 8 edge groups
    int ll = lane & 7;    // channels ll*2, ll*2+1
    float sdn = sd[node];
    float es = lrelu(ss[node] + sdn);
    float a0 = 0.f, a1 = 0.f, sm = 0.f;
#pragma unroll 2
    for (int i = grp; i < dg; i += 8) {
        int s = srcs[off + i];
        float w = __expf(lrelu(ss[s] + sdn));
        sm += w;
        uint hv = hb2[s * 8 + ll];
        a0 = fmaf(w, bfl(hv), a0);
        a1 = fmaf(w, bfh(hv), a1);
    }
#pragma unroll
    for (int d = 8; d <= 32; d <<= 1) {
        a0 += __shfl_xor(a0, d, 64);
        a1 += __shfl_xor(a1, d, 64);
        sm += __shfl_xor(sm, d, 64);
    }
    float wS = __expf(es);
    sm += wS;
    uint hvS = hb2[node * 8 + ll];
    a0 = fmaf(wS, bfl(hvS), a0);
    a1 = fmaf(wS, bfh(hvS), a1);
    float inv = 1.f / (sm + EPS_SM);
    if (grp == 0) {
        float2 o = make_float2(a0 * inv + bias[ll * 2], a1 * inv + bias[ll * 2 + 1]);
        *(float2*)&out[(long)node * 16 + ll * 2] = o;
    }
}

// ---------------- BatchNorm stats ----------------
__global__ void bn_stats(const float* __restrict__ X, float* __restrict__ sums, int n) {
    long total = (long)n * 128;
    int T = gridDim.x * blockDim.x;  // multiple of 128
    long tid = (long)blockIdx.x * blockDim.x + threadIdx.x;
    int ch = (int)(tid & 127);
    float s = 0.f, s2 = 0.f;
    for (long i = tid; i < total; i += T) {
        float v = X[i];
        s += v;
        s2 = fmaf(v, v, s2);
    }
    atomicAdd(&sums[ch], s);
    atomicAdd(&sums[128 + ch], s2);
}

extern "C" void kernel_launch(void* const* d_in, const int* in_sizes, int n_in,
                              void* d_out, int out_size, void* d_ws, size_t ws_size,
                              hipStream_t stream) {
    const float* x = (const float*)d_in[0];
    const int* ei = (const int*)d_in[1];
    const float* W0 = (const float*)d_in[2];
    const float* as0 = (const float*)d_in[3];
    const float* ad0 = (const float*)d_in[4];
    const float* b0 = (const float*)d_in[5];
    const float* g0 = (const float*)d_in[6];
    const float* be0 = (const float*)d_in[7];
    const float* W1 = (const float*)d_in[8];
    const float* as1 = (const float*)d_in[9];
    const float* ad1 = (const float*)d_in[10];
    const float* b1 = (const float*)d_in[11];
    const float* g1 = (const float*)d_in[12];
    const float* be1 = (const float*)d_in[13];
    const float* W2 = (const float*)d_in[14];
    const float* as2 = (const float*)d_in[15];
    const float* ad2 = (const float*)d_in[16];
    const float* b2 = (const float*)d_in[17];

    int n = in_sizes[0] / 128;
    int E = in_sizes[1] / 2;
    const int* srcA = ei;
    const int* dstA = ei + E;

    char* base = (char*)d_ws;
    auto alloc = [&](size_t bytes) {
        char* p = base;
        base += (bytes + 255) & ~(size_t)255;
        return p;
    };
    ushort* hb = (ushort*)alloc((size_t)n * 128 * 2);  // bf16 h (layers 0/1)
    float* act = (float*)alloc((size_t)n * 128 * 4);   // fp32 aggregate (BN input)
    ushort* h2b = (ushort*)alloc((size_t)n * 16 * 2);  // bf16 h (layer 2)
    float* ssb = (float*)alloc((size_t)n * 4 * 4);
    float* sdb = (float*)alloc((size_t)n * 4 * 4);
    float* sums = (float*)alloc(256 * 4);
    int* deg = (int*)alloc((size_t)n * 4);
    int* offs = (int*)alloc((size_t)n * 4);
    int* cur = (int*)alloc((size_t)n * 4);
    int* srcs = (int*)alloc((size_t)E * 4);

    float* out = (float*)d_out;

    // ---- CSR build (edge_index is layer-invariant) ----
    hipMemsetAsync(deg, 0, (size_t)n * 4, stream);
    hist_kernel<<<1024, 256, 0, stream>>>(dstA, E, deg);
    scan_kernel<<<1, 1024, 0, stream>>>(deg, offs, cur, n);
    scatter_kernel<<<1024, 256, 0, stream>>>(srcA, dstA, E, cur, srcs);

    int gGemm128 = (n + 31) / 32;
    int gGemm16 = (n + 63) / 64;
    int gWave = (n + 3) / 4;

    // ---- layer 0 ----
    gemm_k128<128, 32, 256, 64, false, 4><<<gGemm128, 256, 0, stream>>>(
        x, W0, hb, n, sums, g0, be0, as0, ad0, ssb, sdb);
    gat_gather4<<<gWave, 256, 0, stream>>>((const uint*)hb, ssb, sdb, offs, deg, srcs, b0, act, n);
    hipMemsetAsync(sums, 0, 256 * 4, stream);
    bn_stats<<<512, 256, 0, stream>>>(act, sums, n);

    // ---- layer 1 (BN+ELU fused into GEMM X-staging) ----
    gemm_k128<128, 32, 256, 64, true, 4><<<gGemm128, 256, 0, stream>>>(
        act, W1, hb, n, sums, g0, be0, as1, ad1, ssb, sdb);
    gat_gather4<<<gWave, 256, 0, stream>>>((const uint*)hb, ssb, sdb, offs, deg, srcs, b1, act, n);
    hipMemsetAsync(sums, 0, 256 * 4, stream);
    bn_stats<<<512, 256, 0, stream>>>(act, sums, n);

    // ---- layer 2 ----
    gemm_k128<16, 64, 128, 128, true, 1><<<gGemm16, 128, 0, stream>>>(
        act, W2, h2b, n, sums, g1, be1, as2, ad2, ssb, sdb);
    gat_gather1<<<gWave, 256, 0, stream>>>((const uint*)h2b, ssb, sdb, offs, deg, srcs, b2, out, n);
}

// Round 4
// 318.765 us; speedup vs baseline: 2.1464x; 1.2843x over previous
//
#include <hip/hip_runtime.h>
#include <hip/hip_bf16.h>
#include <math.h>

#define NEG_SLOPE 0.2f
#define EPS_SM 1e-16f
#define BN_EPS 1e-5f
#define RANK_BLOCKS 1024

__device__ __forceinline__ float lrelu(float x) { return x > 0.f ? x : NEG_SLOPE * x; }
// fp32 -> bf16 round-to-nearest-even
__device__ __forceinline__ ushort f2bf(float f) {
    uint u = __float_as_uint(f);
    return (ushort)((u + 0x7FFFu + ((u >> 16) & 1u)) >> 16);
}
__device__ __forceinline__ float bfl(uint u) { return __uint_as_float(u << 16); }
__device__ __forceinline__ float bfh(uint u) { return __uint_as_float(u & 0xFFFF0000u); }

// ---- GEMM: Hb[n,NC](bf16) = bnelu?(X[n,128]) @ W[128,NC], scores fused in epilogue.
// ---- Optionally co-dispatches the CSR rank/hist pass in extra trailing blocks.
template <int NC, int ROWS, int NT, int KSTEP, bool BNELU, int HEADS, bool RANKFUSE>
__global__ __launch_bounds__(NT) void gemm_k128(
    const float* __restrict__ X, const float* __restrict__ W, ushort* __restrict__ Hb, int n,
    const float* __restrict__ sums, const float* __restrict__ g, const float* __restrict__ be,
    const float* __restrict__ as_, const float* __restrict__ ad_,
    float* __restrict__ ss, float* __restrict__ sd,
    int gemmBlocks, const int* __restrict__ dstE, int E, int* __restrict__ deg,
    ushort* __restrict__ rank) {
    if constexpr (RANKFUSE) {
        int rb = (int)blockIdx.x - gemmBlocks;
        if (rb >= 0) {  // CSR rank pass: deg histogram + per-edge rank in one atomic
            int T = RANK_BLOCKS * NT;
            for (int i = rb * NT + (int)threadIdx.x; i < E; i += T)
                rank[i] = (ushort)atomicAdd(&deg[dstE[i]], 1);
            return;
        }
    }
    constexpr int CG = NC / 4;      // column groups (4 cols each)
    constexpr int RG = NT / CG;     // row groups
    constexpr int RPT = ROWS / RG;  // rows per thread
    constexpr int C = NC / HEADS;   // channels per head
    constexpr int TPH = C / 4;      // threads covering one head's channels
    __shared__ float Wl[KSTEP][NC];
    __shared__ float Xl[ROWS][128];
    int tid = threadIdx.x;
    int row0 = blockIdx.x * ROWS;
    float inv_n = 1.f / (float)n;
    // stage X tile (optionally fused BatchNorm + ELU)
    for (int i = tid; i < ROWS * 32; i += NT) {
        int r = i >> 5, q = i & 31;
        int gr = row0 + r;
        float4 v = make_float4(0.f, 0.f, 0.f, 0.f);
        if (gr < n) v = ((const float4*)(X + (long)gr * 128))[q];
        if constexpr (BNELU) {
            int c0 = q * 4;
            float m, vv, sc, y;
            m = sums[c0] * inv_n; vv = fmaxf(sums[128 + c0] * inv_n - m * m, 0.f);
            sc = rsqrtf(vv + BN_EPS) * g[c0]; y = (v.x - m) * sc + be[c0];
            v.x = y > 0.f ? y : expm1f(y);
            m = sums[c0 + 1] * inv_n; vv = fmaxf(sums[129 + c0] * inv_n - m * m, 0.f);
            sc = rsqrtf(vv + BN_EPS) * g[c0 + 1]; y = (v.y - m) * sc + be[c0 + 1];
            v.y = y > 0.f ? y : expm1f(y);
            m = sums[c0 + 2] * inv_n; vv = fmaxf(sums[130 + c0] * inv_n - m * m, 0.f);
            sc = rsqrtf(vv + BN_EPS) * g[c0 + 2]; y = (v.z - m) * sc + be[c0 + 2];
            v.z = y > 0.f ? y : expm1f(y);
            m = sums[c0 + 3] * inv_n; vv = fmaxf(sums[131 + c0] * inv_n - m * m, 0.f);
            sc = rsqrtf(vv + BN_EPS) * g[c0 + 3]; y = (v.w - m) * sc + be[c0 + 3];
            v.w = y > 0.f ? y : expm1f(y);
        }
        ((float4*)&Xl[r][0])[q] = v;
    }
    int cg = tid % CG, rg = tid / CG;
    float acc[RPT][4] = {};
    for (int kb = 0; kb < 128; kb += KSTEP) {
        __syncthreads();
        for (int i = tid; i < KSTEP * NC / 4; i += NT)
            ((float4*)Wl)[i] = ((const float4*)(W + kb * NC))[i];
        __syncthreads();
        for (int kk = 0; kk < KSTEP; ++kk) {
            float4 w = *(const float4*)&Wl[kk][cg * 4];
            int k = kb + kk;
#pragma unroll
            for (int r = 0; r < RPT; ++r) {
                float xv = Xl[rg * RPT + r][k];
                acc[r][0] = fmaf(xv, w.x, acc[r][0]);
                acc[r][1] = fmaf(xv, w.y, acc[r][1]);
                acc[r][2] = fmaf(xv, w.z, acc[r][2]);
                acc[r][3] = fmaf(xv, w.w, acc[r][3]);
            }
        }
    }
    // write bf16 h
#pragma unroll
    for (int r = 0; r < RPT; ++r) {
        int gr = row0 + rg * RPT + r;
        if (gr < n) {
            uint2 p;
            p.x = (uint)f2bf(acc[r][0]) | ((uint)f2bf(acc[r][1]) << 16);
            p.y = (uint)f2bf(acc[r][2]) | ((uint)f2bf(acc[r][3]) << 16);
            *(uint2*)&Hb[(long)gr * NC + cg * 4] = p;
        }
    }
    // fused attention scores: reduce over the TPH threads covering one head
    int head = cg / TPH;
    float4 av = *(const float4*)&as_[cg * 4];
    float4 dv = *(const float4*)&ad_[cg * 4];
#pragma unroll
    for (int r = 0; r < RPT; ++r) {
        float ps = acc[r][0] * av.x + acc[r][1] * av.y + acc[r][2] * av.z + acc[r][3] * av.w;
        float pd = acc[r][0] * dv.x + acc[r][1] * dv.y + acc[r][2] * dv.z + acc[r][3] * dv.w;
#pragma unroll
        for (int d = 1; d < TPH; d <<= 1) {
            ps += __shfl_xor(ps, d, 64);
            pd += __shfl_xor(pd, d, 64);
        }
        int gr = row0 + rg * RPT + r;
        if ((cg & (TPH - 1)) == 0 && gr < n) {
            ss[(long)gr * HEADS + head] = ps;
            sd[(long)gr * HEADS + head] = pd;
        }
    }
}

// ---------------- CSR build: vectorized single-block scan (int4) ----------------
__global__ __launch_bounds__(1024) void scan_kernel(const int* __restrict__ deg,
                                                    int* __restrict__ offs, int n) {
    __shared__ int wsum[16];
    __shared__ int wpre[16];
    __shared__ int carry_s;
    int tid = threadIdx.x;
    int lane = tid & 63;
    int w = tid >> 6;
    if (tid == 0) carry_s = 0;
    __syncthreads();
    int nv = (n + 3) >> 2;  // int4 groups
    for (int base = 0; base < nv; base += 1024) {
        int carry = carry_s;
        int gi = base + tid;
        int e0 = gi * 4;
        int4 v = make_int4(0, 0, 0, 0);
        if (e0 + 3 < n) {
            v = ((const int4*)deg)[gi];
        } else if (e0 < n) {
            v.x = deg[e0];
            if (e0 + 1 < n) v.y = deg[e0 + 1];
            if (e0 + 2 < n) v.z = deg[e0 + 2];
        }
        int tsum = v.x + v.y + v.z + v.w;
        int incl = tsum;
#pragma unroll
        for (int d = 1; d < 64; d <<= 1) {
            int t = __shfl_up(incl, d, 64);
            if (lane >= d) incl += t;
        }
        if (lane == 63) wsum[w] = incl;
        __syncthreads();
        if (w == 0 && lane < 16) {
            int s = wsum[lane];
#pragma unroll
            for (int d = 1; d < 16; d <<= 1) {
                int t = __shfl_up(s, d, 64);
                if (lane >= d) s += t;
            }
            wpre[lane] = s;
        }
        __syncthreads();
        int wbase = (w == 0) ? 0 : wpre[w - 1];
        int ex = carry + wbase + incl - tsum;
        if (e0 < n) {
            int4 o;
            o.x = ex;
            o.y = ex + v.x;
            o.z = o.y + v.y;
            o.w = o.z + v.z;
            if (e0 + 3 < n) {
                ((int4*)offs)[gi] = o;
            } else {
                offs[e0] = o.x;
                if (e0 + 1 < n) offs[e0 + 1] = o.y;
                if (e0 + 2 < n) offs[e0 + 2] = o.z;
            }
        }
        __syncthreads();
        if (tid == 1023) carry_s = carry + wpre[15];
        __syncthreads();
    }
}

// atomic-free scatter: position = offs[dst] + precomputed rank
__global__ void scatter_kernel(const int* __restrict__ src, const int* __restrict__ dst,
                               const ushort* __restrict__ rank, const int* __restrict__ offs,
                               int E, int* __restrict__ srcs) {
    int i = blockIdx.x * blockDim.x + threadIdx.x;
    int T = gridDim.x * blockDim.x;
    for (; i < E; i += T) {
        int d = dst[i];
        srcs[offs[d] + (int)rank[i]] = src[i];
    }
}

// ---- GAT gather, 4 heads x 32ch: single pass, 4 edge-groups x 16 lanes x 8ch ----
__global__ __launch_bounds__(256) void gat_gather4(
    const uint* __restrict__ hb, const float* __restrict__ ss, const float* __restrict__ sd,
    const int* __restrict__ offs, const int* __restrict__ deg, const int* __restrict__ srcs,
    const float* __restrict__ bias, float* __restrict__ out, int n) {
    int wid = threadIdx.x >> 6;
    int lane = threadIdx.x & 63;
    int node = blockIdx.x * 4 + wid;
    if (node >= n) return;
    int off = offs[node];
    int dg = deg[node];
    int grp = lane >> 4;   // edge group (4 edges in flight per wave)
    int ll = lane & 15;    // channels ll*8 .. ll*8+7
    int hd = ll >> 2;      // head of those channels
    float sdn = sd[node * 4 + hd];
    float es = lrelu(ss[node * 4 + hd] + sdn);  // self-loop score (no max shift:
                                                // softmax shift-invariant, scores bounded)
    const uint* hrow = hb + ll * 4;
    float acc[8] = {};
    float sm = 0.f;
#pragma unroll 2
    for (int i = grp; i < dg; i += 4) {
        int s = srcs[off + i];
        float w = __expf(lrelu(ss[s * 4 + hd] + sdn));
        sm += w;
        uint4 hv = *(const uint4*)(hrow + (long)s * 64);
        acc[0] = fmaf(w, bfl(hv.x), acc[0]);
        acc[1] = fmaf(w, bfh(hv.x), acc[1]);
        acc[2] = fmaf(w, bfl(hv.y), acc[2]);
        acc[3] = fmaf(w, bfh(hv.y), acc[3]);
        acc[4] = fmaf(w, bfl(hv.z), acc[4]);
        acc[5] = fmaf(w, bfh(hv.z), acc[5]);
        acc[6] = fmaf(w, bfl(hv.w), acc[6]);
        acc[7] = fmaf(w, bfh(hv.w), acc[7]);
    }
#pragma unroll
    for (int j = 0; j < 8; ++j) {
        acc[j] += __shfl_xor(acc[j], 16, 64);
        acc[j] += __shfl_xor(acc[j], 32, 64);
    }
    sm += __shfl_xor(sm, 16, 64);
    sm += __shfl_xor(sm, 32, 64);
    // self loop
    float wS = __expf(es);
    sm += wS;
    uint4 hvS = *(const uint4*)(hrow + (long)node * 64);
    acc[0] = fmaf(wS, bfl(hvS.x), acc[0]);
    acc[1] = fmaf(wS, bfh(hvS.x), acc[1]);
    acc[2] = fmaf(wS, bfl(hvS.y), acc[2]);
    acc[3] = fmaf(wS, bfh(hvS.y), acc[3]);
    acc[4] = fmaf(wS, bfl(hvS.z), acc[4]);
    acc[5] = fmaf(wS, bfh(hvS.z), acc[5]);
    acc[6] = fmaf(wS, bfl(hvS.w), acc[6]);
    acc[7] = fmaf(wS, bfh(hvS.w), acc[7]);
    float inv = 1.f / (sm + EPS_SM);
    if (grp == 0) {
        float4 bA = *(const float4*)&bias[ll * 8];
        float4 bB = *(const float4*)&bias[ll * 8 + 4];
        float4 o0 = make_float4(acc[0] * inv + bA.x, acc[1] * inv + bA.y,
                                acc[2] * inv + bA.z, acc[3] * inv + bA.w);
        float4 o1 = make_float4(acc[4] * inv + bB.x, acc[5] * inv + bB.y,
                                acc[6] * inv + bB.z, acc[7] * inv + bB.w);
        *(float4*)&out[(long)node * 128 + ll * 8] = o0;
        *(float4*)&out[(long)node * 128 + ll * 8 + 4] = o1;
    }
}

// ---- GAT gather, 1 head x 16ch: single pass, 8 edge-groups x 8 lanes x 2ch ----
__global__ __launch_bounds__(256) void gat_gather1(
    const uint* __restrict__ hb2, const float* __restrict__ ss, const float* __restrict__ sd,
    const int* __restrict__ offs, const int* __restrict__ deg, const int* __restrict__ srcs,
    const float* __restrict__ bias, float* __restrict__ out, int n) {
    int wid = threadIdx.x >> 6;
    int lane = threadIdx.x & 63;
    int node = blockIdx.x * 4 + wid;
    if (node >= n) return;
    int off = offs[node];
    int dg = deg[node];
    int grp = lane >> 3;  // 8 edge groups
    int ll = lane & 7;    // channels ll*2, ll*2+1
    float sdn = sd[node];
    float es = lrelu(ss[node] + sdn);
    float a0 = 0.f, a1 = 0.f, sm = 0.f;
#pragma unroll 2
    for (int i = grp; i < dg; i += 8) {
        int s = srcs[off + i];
        float w = __expf(lrelu(ss[s] + sdn));
        sm += w;
        uint hv = hb2[s * 8 + ll];
        a0 = fmaf(w, bfl(hv), a0);
        a1 = fmaf(w, bfh(hv), a1);
    }
#pragma unroll
    for (int d = 8; d <= 32; d <<= 1) {
        a0 += __shfl_xor(a0, d, 64);
        a1 += __shfl_xor(a1, d, 64);
        sm += __shfl_xor(sm, d, 64);
    }
    float wS = __expf(es);
    sm += wS;
    uint hvS = hb2[node * 8 + ll];
    a0 = fmaf(wS, bfl(hvS), a0);
    a1 = fmaf(wS, bfh(hvS), a1);
    float inv = 1.f / (sm + EPS_SM);
    if (grp == 0) {
        float2 o = make_float2(a0 * inv + bias[ll * 2], a1 * inv + bias[ll * 2 + 1]);
        *(float2*)&out[(long)node * 16 + ll * 2] = o;
    }
}

// ---------------- BatchNorm stats ----------------
__global__ void bn_stats(const float* __restrict__ X, float* __restrict__ sums, int n) {
    long total = (long)n * 128;
    int T = gridDim.x * blockDim.x;  // multiple of 128
    long tid = (long)blockIdx.x * blockDim.x + threadIdx.x;
    int ch = (int)(tid & 127);
    float s = 0.f, s2 = 0.f;
    for (long i = tid; i < total; i += T) {
        float v = X[i];
        s += v;
        s2 = fmaf(v, v, s2);
    }
    atomicAdd(&sums[ch], s);
    atomicAdd(&sums[128 + ch], s2);
}

extern "C" void kernel_launch(void* const* d_in, const int* in_sizes, int n_in,
                              void* d_out, int out_size, void* d_ws, size_t ws_size,
                              hipStream_t stream) {
    const float* x = (const float*)d_in[0];
    const int* ei = (const int*)d_in[1];
    const float* W0 = (const float*)d_in[2];
    const float* as0 = (const float*)d_in[3];
    const float* ad0 = (const float*)d_in[4];
    const float* b0 = (const float*)d_in[5];
    const float* g0 = (const float*)d_in[6];
    const float* be0 = (const float*)d_in[7];
    const float* W1 = (const float*)d_in[8];
    const float* as1 = (const float*)d_in[9];
    const float* ad1 = (const float*)d_in[10];
    const float* b1 = (const float*)d_in[11];
    const float* g1 = (const float*)d_in[12];
    const float* be1 = (const float*)d_in[13];
    const float* W2 = (const float*)d_in[14];
    const float* as2 = (const float*)d_in[15];
    const float* ad2 = (const float*)d_in[16];
    const float* b2 = (const float*)d_in[17];

    int n = in_sizes[0] / 128;
    int E = in_sizes[1] / 2;
    const int* srcA = ei;
    const int* dstA = ei + E;

    char* base = (char*)d_ws;
    auto alloc = [&](size_t bytes) {
        char* p = base;
        base += (bytes + 255) & ~(size_t)255;
        return p;
    };
    ushort* hb = (ushort*)alloc((size_t)n * 128 * 2);  // bf16 h (layers 0/1)
    float* act = (float*)alloc((size_t)n * 128 * 4);   // fp32 aggregate (BN input)
    ushort* h2b = (ushort*)alloc((size_t)n * 16 * 2);  // bf16 h (layer 2)
    float* ssb = (float*)alloc((size_t)n * 4 * 4);
    float* sdb = (float*)alloc((size_t)n * 4 * 4);
    float* sums = (float*)alloc(512 * 4);  // [0:256) layer0 stats, [256:512) layer1 stats
    int* deg = (int*)alloc((size_t)n * 4);
    int* offs = (int*)alloc((size_t)n * 4);
    ushort* rank = (ushort*)alloc((size_t)E * 2);
    int* srcs = (int*)alloc((size_t)E * 4);
    float* sums0 = sums;
    float* sums1 = sums + 256;

    float* out = (float*)d_out;

    hipMemsetAsync(deg, 0, (size_t)n * 4, stream);
    hipMemsetAsync(sums, 0, 512 * 4, stream);

    int gGemm128 = (n + 31) / 32;
    int gGemm16 = (n + 63) / 64;
    int gWave = (n + 3) / 4;

    // ---- layer 0 GEMM co-dispatched with CSR rank/hist pass ----
    gemm_k128<128, 32, 256, 64, false, 4, true><<<gGemm128 + RANK_BLOCKS, 256, 0, stream>>>(
        x, W0, hb, n, sums0, g0, be0, as0, ad0, ssb, sdb, gGemm128, dstA, E, deg, rank);
    scan_kernel<<<1, 1024, 0, stream>>>(deg, offs, n);
    scatter_kernel<<<2048, 256, 0, stream>>>(srcA, dstA, rank, offs, E, srcs);

    gat_gather4<<<gWave, 256, 0, stream>>>((const uint*)hb, ssb, sdb, offs, deg, srcs, b0, act, n);
    bn_stats<<<512, 256, 0, stream>>>(act, sums0, n);

    // ---- layer 1 (BN+ELU fused into GEMM X-staging) ----
    gemm_k128<128, 32, 256, 64, true, 4, false><<<gGemm128, 256, 0, stream>>>(
        act, W1, hb, n, sums0, g0, be0, as1, ad1, ssb, sdb, 0, nullptr, 0, nullptr, nullptr);
    gat_gather4<<<gWave, 256, 0, stream>>>((const uint*)hb, ssb, sdb, offs, deg, srcs, b1, act, n);
    bn_stats<<<512, 256, 0, stream>>>(act, sums1, n);

    // ---- layer 2 ----
    gemm_k128<16, 64, 128, 128, true, 1, false><<<gGemm16, 128, 0, stream>>>(
        act, W2, h2b, n, sums1, g1, be1, as2, ad2, ssb, sdb, 0, nullptr, 0, nullptr, nullptr);
    gat_gather1<<<gWave, 256, 0, stream>>>((const uint*)h2b, ssb, sdb, offs, deg, srcs, b2, out, n);
}

// Round 5
// 297.118 us; speedup vs baseline: 2.3028x; 1.0729x over previous
//
#include <hip/hip_runtime.h>
#include <hip/hip_bf16.h>
#include <math.h>

#define NEG_SLOPE 0.2f
#define EPS_SM 1e-16f
#define BN_EPS 1e-5f
#define RANK_BLOCKS 1024

typedef __attribute__((ext_vector_type(8))) short bf16x8;
typedef __attribute__((ext_vector_type(4))) float f32x4;

__device__ __forceinline__ float lrelu(float x) { return x > 0.f ? x : NEG_SLOPE * x; }
// fp32 -> bf16 round-to-nearest-even
__device__ __forceinline__ ushort f2bf(float f) {
    uint u = __float_as_uint(f);
    return (ushort)((u + 0x7FFFu + ((u >> 16) & 1u)) >> 16);
}
__device__ __forceinline__ float bfl(uint u) { return __uint_as_float(u << 16); }
__device__ __forceinline__ float bfh(uint u) { return __uint_as_float(u & 0xFFFF0000u); }

// ---- pack W[128][NC] fp32 -> bf16 in B-fragment order [kstep][frag][lane][8] ----
__global__ void pack_w(const float* __restrict__ W0, const float* __restrict__ W1,
                       const float* __restrict__ W2, ushort* __restrict__ P0,
                       ushort* __restrict__ P1, ushort* __restrict__ P2) {
    int i = blockIdx.x * blockDim.x + threadIdx.x;
    const float* W;
    ushort* P;
    int NC, s;
    if (i < 16384) { W = W0; P = P0; NC = 128; s = i; }
    else if (i < 32768) { W = W1; P = P1; NC = 128; s = i - 16384; }
    else if (i < 34816) { W = W2; P = P2; NC = 16; s = i - 32768; }
    else return;
    int k = s / NC, col = s % NC;
    int CT = NC >> 4;
    int dst = (((k >> 5) * CT + (col >> 4)) << 9) +
              (((col & 15) | (((k >> 3) & 3) << 4)) << 3) + (k & 7);
    P[dst] = f2bf(W[s]);
}

// ---- MFMA GEMM: Hb[n,NC](bf16) = bnelu?(X[n,128]) @ W, scores in epilogue ----
// 64 rows x NC cols per block, 4 waves x 16 rows, mfma_f32_16x16x32_bf16.
template <int NC, bool BNELU, int HEADS, bool RANKFUSE>
__global__ __launch_bounds__(256) void gemm_mfma(
    const float* __restrict__ X, const ushort* __restrict__ Wp, ushort* __restrict__ Hb, int n,
    const float* __restrict__ sums, const float* __restrict__ g, const float* __restrict__ be,
    const float* __restrict__ as_, const float* __restrict__ ad_,
    float* __restrict__ ss, float* __restrict__ sd,
    int gemmBlocks, const int* __restrict__ dstE, int E, int* __restrict__ deg,
    ushort* __restrict__ rank) {
    if constexpr (RANKFUSE) {
        int rb = (int)blockIdx.x - gemmBlocks;
        if (rb >= 0) {  // CSR rank pass: deg histogram + per-edge rank in one atomic
            int T = RANK_BLOCKS * 256;
            for (int i = rb * 256 + (int)threadIdx.x; i < E; i += T)
                rank[i] = (ushort)atomicAdd(&deg[dstE[i]], 1);
            return;
        }
    }
    constexpr int CT = NC / 16;        // column fragments
    constexpr int FPH = NC / HEADS / 16;  // fragments per head
    __shared__ __align__(16) ushort Xb[64 * 128];   // swizzled bf16 X tile
    __shared__ __align__(16) ushort Wl[CT * 2048];  // fragment-ordered bf16 W
    int tid = threadIdx.x;
    int row0 = blockIdx.x * 64;
    // stage W (linear copy, conflict-free)
    for (int i = tid; i < CT * 256; i += 256) ((uint4*)Wl)[i] = ((const uint4*)Wp)[i];
    // stage X: fp32 -> (BN+ELU) -> bf16, swizzled (s = (k>>3) ^ (row&15))
    float inv_n = 1.f / (float)n;
#pragma unroll
    for (int i = 0; i < 8; ++i) {
        int idx = tid + i * 256;  // over 64*32 float4
        int row = idx >> 5, q = idx & 31;
        int gr = row0 + row;
        float4 v = make_float4(0.f, 0.f, 0.f, 0.f);
        if (gr < n) v = ((const float4*)(X + (long)gr * 128))[q];
        if constexpr (BNELU) {
            int c0 = q * 4;
            float m, vv, sc, y;
            m = sums[c0] * inv_n; vv = fmaxf(sums[128 + c0] * inv_n - m * m, 0.f);
            sc = rsqrtf(vv + BN_EPS) * g[c0]; y = (v.x - m) * sc + be[c0];
            v.x = y > 0.f ? y : expm1f(y);
            m = sums[c0 + 1] * inv_n; vv = fmaxf(sums[129 + c0] * inv_n - m * m, 0.f);
            sc = rsqrtf(vv + BN_EPS) * g[c0 + 1]; y = (v.y - m) * sc + be[c0 + 1];
            v.y = y > 0.f ? y : expm1f(y);
            m = sums[c0 + 2] * inv_n; vv = fmaxf(sums[130 + c0] * inv_n - m * m, 0.f);
            sc = rsqrtf(vv + BN_EPS) * g[c0 + 2]; y = (v.z - m) * sc + be[c0 + 2];
            v.z = y > 0.f ? y : expm1f(y);
            m = sums[c0 + 3] * inv_n; vv = fmaxf(sums[131 + c0] * inv_n - m * m, 0.f);
            sc = rsqrtf(vv + BN_EPS) * g[c0 + 3]; y = (v.w - m) * sc + be[c0 + 3];
            v.w = y > 0.f ? y : expm1f(y);
        }
        ushort4 p = make_ushort4(f2bf(v.x), f2bf(v.y), f2bf(v.z), f2bf(v.w));
        int s = (q >> 1) ^ (row & 15);
        *(ushort4*)&Xb[row * 128 + s * 8 + (q & 1) * 4] = p;
    }
    __syncthreads();
    int lane = tid & 63;
    int w = tid >> 6;
    int r0 = w * 16;
    int lrow = lane & 15, lhi = lane >> 4;
    f32x4 zero = {0.f, 0.f, 0.f, 0.f};
    f32x4 acc[CT];
#pragma unroll
    for (int f = 0; f < CT; ++f) acc[f] = zero;
    const ushort* xrow = &Xb[(r0 + lrow) * 128];
#pragma unroll
    for (int ks = 0; ks < 4; ++ks) {
        int kg = ks * 4 + lhi;
        bf16x8 a = *(const bf16x8*)&xrow[(kg ^ lrow) << 3];
#pragma unroll
        for (int f = 0; f < CT; ++f) {
            bf16x8 b = *(const bf16x8*)&Wl[((ks * CT + f) * 64 + lane) * 8];
            acc[f] = __builtin_amdgcn_mfma_f32_16x16x32_bf16(a, b, acc[f], 0, 0, 0);
        }
    }
    // write bf16 h: C layout col = lane&15, row = (lane>>4)*4 + j
#pragma unroll
    for (int f = 0; f < CT; ++f)
#pragma unroll
        for (int j = 0; j < 4; ++j) {
            int gr = row0 + r0 + lhi * 4 + j;
            if (gr < n) Hb[(long)gr * NC + f * 16 + lrow] = f2bf(acc[f][j]);
        }
    // fused attention scores
    float asv[CT], adv[CT];
#pragma unroll
    for (int f = 0; f < CT; ++f) {
        asv[f] = as_[f * 16 + lrow];
        adv[f] = ad_[f * 16 + lrow];
    }
#pragma unroll
    for (int h = 0; h < HEADS; ++h) {
        float ps[4] = {}, pd[4] = {};
#pragma unroll
        for (int fi = 0; fi < FPH; ++fi) {
            int f = h * FPH + fi;
#pragma unroll
            for (int j = 0; j < 4; ++j) {
                ps[j] = fmaf(acc[f][j], asv[f], ps[j]);
                pd[j] = fmaf(acc[f][j], adv[f], pd[j]);
            }
        }
#pragma unroll
        for (int j = 0; j < 4; ++j) {
#pragma unroll
            for (int d = 1; d < 16; d <<= 1) {
                ps[j] += __shfl_xor(ps[j], d, 64);
                pd[j] += __shfl_xor(pd[j], d, 64);
            }
            int gr = row0 + r0 + lhi * 4 + j;
            if (lrow == 0 && gr < n) {
                ss[(long)gr * HEADS + h] = ps[j];
                sd[(long)gr * HEADS + h] = pd[j];
            }
        }
    }
}

// ---------------- CSR build: vectorized single-block scan (int4) ----------------
__global__ __launch_bounds__(1024) void scan_kernel(const int* __restrict__ deg,
                                                    int* __restrict__ offs, int n) {
    __shared__ int wsum[16];
    __shared__ int wpre[16];
    __shared__ int carry_s;
    int tid = threadIdx.x;
    int lane = tid & 63;
    int w = tid >> 6;
    if (tid == 0) carry_s = 0;
    __syncthreads();
    int nv = (n + 3) >> 2;  // int4 groups
    for (int base = 0; base < nv; base += 1024) {
        int carry = carry_s;
        int gi = base + tid;
        int e0 = gi * 4;
        int4 v = make_int4(0, 0, 0, 0);
        if (e0 + 3 < n) {
            v = ((const int4*)deg)[gi];
        } else if (e0 < n) {
            v.x = deg[e0];
            if (e0 + 1 < n) v.y = deg[e0 + 1];
            if (e0 + 2 < n) v.z = deg[e0 + 2];
        }
        int tsum = v.x + v.y + v.z + v.w;
        int incl = tsum;
#pragma unroll
        for (int d = 1; d < 64; d <<= 1) {
            int t = __shfl_up(incl, d, 64);
            if (lane >= d) incl += t;
        }
        if (lane == 63) wsum[w] = incl;
        __syncthreads();
        if (w == 0 && lane < 16) {
            int s = wsum[lane];
#pragma unroll
            for (int d = 1; d < 16; d <<= 1) {
                int t = __shfl_up(s, d, 64);
                if (lane >= d) s += t;
            }
            wpre[lane] = s;
        }
        __syncthreads();
        int wbase = (w == 0) ? 0 : wpre[w - 1];
        int ex = carry + wbase + incl - tsum;
        if (e0 < n) {
            int4 o;
            o.x = ex;
            o.y = ex + v.x;
            o.z = o.y + v.y;
            o.w = o.z + v.z;
            if (e0 + 3 < n) {
                ((int4*)offs)[gi] = o;
            } else {
                offs[e0] = o.x;
                if (e0 + 1 < n) offs[e0 + 1] = o.y;
                if (e0 + 2 < n) offs[e0 + 2] = o.z;
            }
        }
        __syncthreads();
        if (tid == 1023) carry_s = carry + wpre[15];
        __syncthreads();
    }
}

// atomic-free scatter: position = offs[dst] + precomputed rank
__global__ void scatter_kernel(const int* __restrict__ src, const int* __restrict__ dst,
                               const ushort* __restrict__ rank, const int* __restrict__ offs,
                               int E, int* __restrict__ srcs) {
    int i = blockIdx.x * blockDim.x + threadIdx.x;
    int T = gridDim.x * blockDim.x;
    for (; i < E; i += T) {
        int d = dst[i];
        srcs[offs[d] + (int)rank[i]] = src[i];
    }
}

// ---- GAT gather, 4 heads x 32ch: single pass, 4 edge-groups x 16 lanes x 8ch ----
__global__ __launch_bounds__(256) void gat_gather4(
    const uint* __restrict__ hb, const float* __restrict__ ss, const float* __restrict__ sd,
    const int* __restrict__ offs, const int* __restrict__ deg, const int* __restrict__ srcs,
    const float* __restrict__ bias, float* __restrict__ out, int n) {
    int wid = threadIdx.x >> 6;
    int lane = threadIdx.x & 63;
    int node = blockIdx.x * 4 + wid;
    if (node >= n) return;
    int off = offs[node];
    int dg = deg[node];
    int grp = lane >> 4;   // edge group (4 edges in flight per wave)
    int ll = lane & 15;    // channels ll*8 .. ll*8+7
    int hd = ll >> 2;      // head of those channels
    float sdn = sd[node * 4 + hd];
    float es = lrelu(ss[node * 4 + hd] + sdn);  // self-loop score
    const uint* hrow = hb + ll * 4;
    float acc[8] = {};
    float sm = 0.f;
#pragma unroll 2
    for (int i = grp; i < dg; i += 4) {
        int s = srcs[off + i];
        float w = __expf(lrelu(ss[s * 4 + hd] + sdn));
        sm += w;
        uint4 hv = *(const uint4*)(hrow + (long)s * 64);
        acc[0] = fmaf(w, bfl(hv.x), acc[0]);
        acc[1] = fmaf(w, bfh(hv.x), acc[1]);
        acc[2] = fmaf(w, bfl(hv.y), acc[2]);
        acc[3] = fmaf(w, bfh(hv.y), acc[3]);
        acc[4] = fmaf(w, bfl(hv.z), acc[4]);
        acc[5] = fmaf(w, bfh(hv.z), acc[5]);
        acc[6] = fmaf(w, bfl(hv.w), acc[6]);
        acc[7] = fmaf(w, bfh(hv.w), acc[7]);
    }
#pragma unroll
    for (int j = 0; j < 8; ++j) {
        acc[j] += __shfl_xor(acc[j], 16, 64);
        acc[j] += __shfl_xor(acc[j], 32, 64);
    }
    sm += __shfl_xor(sm, 16, 64);
    sm += __shfl_xor(sm, 32, 64);
    float wS = __expf(es);
    sm += wS;
    uint4 hvS = *(const uint4*)(hrow + (long)node * 64);
    acc[0] = fmaf(wS, bfl(hvS.x), acc[0]);
    acc[1] = fmaf(wS, bfh(hvS.x), acc[1]);
    acc[2] = fmaf(wS, bfl(hvS.y), acc[2]);
    acc[3] = fmaf(wS, bfh(hvS.y), acc[3]);
    acc[4] = fmaf(wS, bfl(hvS.z), acc[4]);
    acc[5] = fmaf(wS, bfh(hvS.z), acc[5]);
    acc[6] = fmaf(wS, bfl(hvS.w), acc[6]);
    acc[7] = fmaf(wS, bfh(hvS.w), acc[7]);
    float inv = 1.f / (sm + EPS_SM);
    if (grp == 0) {
        float4 bA = *(const float4*)&bias[ll * 8];
        float4 bB = *(const float4*)&bias[ll * 8 + 4];
        float4 o0 = make_float4(acc[0] * inv + bA.x, acc[1] * inv + bA.y,
                                acc[2] * inv + bA.z, acc[3] * inv + bA.w);
        float4 o1 = make_float4(acc[4] * inv + bB.x, acc[5] * inv + bB.y,
                                acc[6] * inv + bB.z, acc[7] * inv + bB.w);
        *(float4*)&out[(long)node * 128 + ll * 8] = o0;
        *(float4*)&out[(long)node * 128 + ll * 8 + 4] = o1;
    }
}

// ---- GAT gather, 1 head x 16ch: single pass, 8 edge-groups x 8 lanes x 2ch ----
__global__ __launch_bounds__(256) void gat_gather1(
    const uint* __restrict__ hb2, const float* __restrict__ ss, const float* __restrict__ sd,
    const int* __restrict__ offs, const int* __restrict__ deg, const int* __restrict__ srcs,
    const float* __restrict__ bias, float* __restrict__ out, int n) {
    int wid = threadIdx.x >> 6;
    int lane = threadIdx.x & 63;
    int node = blockIdx.x * 4 + wid;
    if (node >= n) return;
    int off = offs[node];
    int dg = deg[node];
    int grp = lane >> 3;  // 8 edge groups
    int ll = lane & 7;    // channels ll*2, ll*2+1
    float sdn = sd[node];
    float es = lrelu(ss[node] + sdn);
    float a0 = 0.f, a1 = 0.f, sm = 0.f;
#pragma unroll 2
    for (int i = grp; i < dg; i += 8) {
        int s = srcs[off + i];
        float w = __expf(lrelu(ss[s] + sdn));
        sm += w;
        uint hv = hb2[s * 8 + ll];
        a0 = fmaf(w, bfl(hv), a0);
        a1 = fmaf(w, bfh(hv), a1);
    }
#pragma unroll
    for (int d = 8; d <= 32; d <<= 1) {
        a0 += __shfl_xor(a0, d, 64);
        a1 += __shfl_xor(a1, d, 64);
        sm += __shfl_xor(sm, d, 64);
    }
    float wS = __expf(es);
    sm += wS;
    uint hvS = hb2[node * 8 + ll];
    a0 = fmaf(wS, bfl(hvS), a0);
    a1 = fmaf(wS, bfh(hvS), a1);
    float inv = 1.f / (sm + EPS_SM);
    if (grp == 0) {
        float2 o = make_float2(a0 * inv + bias[ll * 2], a1 * inv + bias[ll * 2 + 1]);
        *(float2*)&out[(long)node * 16 + ll * 2] = o;
    }
}

// ---------------- BatchNorm stats ----------------
__global__ void bn_stats(const float* __restrict__ X, float* __restrict__ sums, int n) {
    long total = (long)n * 128;
    int T = gridDim.x * blockDim.x;  // multiple of 128
    long tid = (long)blockIdx.x * blockDim.x + threadIdx.x;
    int ch = (int)(tid & 127);
    float s = 0.f, s2 = 0.f;
    for (long i = tid; i < total; i += T) {
        float v = X[i];
        s += v;
        s2 = fmaf(v, v, s2);
    }
    atomicAdd(&sums[ch], s);
    atomicAdd(&sums[128 + ch], s2);
}

extern "C" void kernel_launch(void* const* d_in, const int* in_sizes, int n_in,
                              void* d_out, int out_size, void* d_ws, size_t ws_size,
                              hipStream_t stream) {
    const float* x = (const float*)d_in[0];
    const int* ei = (const int*)d_in[1];
    const float* W0 = (const float*)d_in[2];
    const float* as0 = (const float*)d_in[3];
    const float* ad0 = (const float*)d_in[4];
    const float* b0 = (const float*)d_in[5];
    const float* g0 = (const float*)d_in[6];
    const float* be0 = (const float*)d_in[7];
    const float* W1 = (const float*)d_in[8];
    const float* as1 = (const float*)d_in[9];
    const float* ad1 = (const float*)d_in[10];
    const float* b1 = (const float*)d_in[11];
    const float* g1 = (const float*)d_in[12];
    const float* be1 = (const float*)d_in[13];
    const float* W2 = (const float*)d_in[14];
    const float* as2 = (const float*)d_in[15];
    const float* ad2 = (const float*)d_in[16];
    const float* b2 = (const float*)d_in[17];

    int n = in_sizes[0] / 128;
    int E = in_sizes[1] / 2;
    const int* srcA = ei;
    const int* dstA = ei + E;

    char* base = (char*)d_ws;
    auto alloc = [&](size_t bytes) {
        char* p = base;
        base += (bytes + 255) & ~(size_t)255;
        return p;
    };
    ushort* hb = (ushort*)alloc((size_t)n * 128 * 2);  // bf16 h (layers 0/1)
    float* act = (float*)alloc((size_t)n * 128 * 4);   // fp32 aggregate (BN input)
    ushort* h2b = (ushort*)alloc((size_t)n * 16 * 2);  // bf16 h (layer 2)
    float* ssb = (float*)alloc((size_t)n * 4 * 4);
    float* sdb = (float*)alloc((size_t)n * 4 * 4);
    float* sums = (float*)alloc(512 * 4);  // [0:256) layer0 stats, [256:512) layer1
    int* deg = (int*)alloc((size_t)n * 4);
    int* offs = (int*)alloc((size_t)n * 4);
    ushort* rank = (ushort*)alloc((size_t)E * 2);
    int* srcs = (int*)alloc((size_t)E * 4);
    ushort* Wp0 = (ushort*)alloc(16384 * 2);
    ushort* Wp1 = (ushort*)alloc(16384 * 2);
    ushort* Wp2 = (ushort*)alloc(2048 * 2);
    float* sums0 = sums;
    float* sums1 = sums + 256;

    float* out = (float*)d_out;

    hipMemsetAsync(deg, 0, (size_t)n * 4, stream);
    hipMemsetAsync(sums, 0, 512 * 4, stream);

    pack_w<<<136, 256, 0, stream>>>(W0, W1, W2, Wp0, Wp1, Wp2);

    int gGemm = (n + 63) / 64;
    int gWave = (n + 3) / 4;

    // ---- layer 0 GEMM (MFMA) co-dispatched with CSR rank/hist pass ----
    gemm_mfma<128, false, 4, true><<<gGemm + RANK_BLOCKS, 256, 0, stream>>>(
        x, Wp0, hb, n, sums0, g0, be0, as0, ad0, ssb, sdb, gGemm, dstA, E, deg, rank);
    scan_kernel<<<1, 1024, 0, stream>>>(deg, offs, n);
    scatter_kernel<<<2048, 256, 0, stream>>>(srcA, dstA, rank, offs, E, srcs);

    gat_gather4<<<gWave, 256, 0, stream>>>((const uint*)hb, ssb, sdb, offs, deg, srcs, b0, act, n);
    bn_stats<<<512, 256, 0, stream>>>(act, sums0, n);

    // ---- layer 1 (BN+ELU fused into GEMM X-staging) ----
    gemm_mfma<128, true, 4, false><<<gGemm, 256, 0, stream>>>(
        act, Wp1, hb, n, sums0, g0, be0, as1, ad1, ssb, sdb, 0, nullptr, 0, nullptr, nullptr);
    gat_gather4<<<gWave, 256, 0, stream>>>((const uint*)hb, ssb, sdb, offs, deg, srcs, b1, act, n);
    bn_stats<<<512, 256, 0, stream>>>(act, sums1, n);

    // ---- layer 2 ----
    gemm_mfma<16, true, 1, false><<<gGemm, 256, 0, stream>>>(
        act, Wp2, h2b, n, sums1, g1, be1, as2, ad2, ssb, sdb, 0, nullptr, 0, nullptr, nullptr);
    gat_gather1<<<gWave, 256, 0, stream>>>((const uint*)h2b, ssb, sdb, offs, deg, srcs, b2, out, n);
}